// Round 11
// baseline (21.925 us; speedup 1.0000x reference)
//
#include <hip/hip_runtime.h>

#define NB 4
#define NS 1024
#define NE 128
#define NH 16
#define ND 8

typedef __attribute__((ext_vector_type(4))) _Float16 half4v;
typedef __attribute__((ext_vector_type(8))) _Float16 half8v;
typedef __attribute__((ext_vector_type(2))) _Float16 half2v;
typedef __attribute__((ext_vector_type(4))) float float4v;

#if __has_builtin(__builtin_amdgcn_exp2f)
#define EXP2F(x) __builtin_amdgcn_exp2f(x)
#else
#define EXP2F(x) __expf(0.69314718055994531f * (x))
#endif

// sqrt(log2(e)/sqrt(8)): both QK^T operands carry this -> MFMA out feeds 2^x directly
#define SQRT_ALPHA 0.71423656f

#define MFMA32(A, B, C) __builtin_amdgcn_mfma_f32_16x16x32_f16((A), (B), (C), 0, 0, 0)

static __device__ __forceinline__ half8v cat8(half4v lo, half4v hi) {
    return __builtin_shufflevector(lo, hi, 0, 1, 2, 3, 4, 5, 6, 7);
}
static __device__ __forceinline__ half4v cat4(half2v lo, half2v hi) {
    return __builtin_shufflevector(lo, hi, 0, 1, 2, 3);
}

// ---------------------------------------------------------------------------
// Fused quantum-layer + self-attention, now on NATIVE 16x16x32 f16 MFMA.
// x32 operand = two stacked x16 fragments (slot j=0..3 <-> k=4G+j, j=4..7 <->
// k=16+4G+j, G=lane>>4; per m156 tr-read layout), so:
//   QK: kf8=[kf|0], qf8=[qf|0] (k 8..31 zero-killed)  — same count, native op
//   PV: pa8=[pa_t0|pa_t1], vf8=[vf_t0|vf_t1]          — MFMA count HALVED
// #pragma unroll 1 on the pair loop: peak live regs ~84 < 128 cap (no spills
// — suspected hidden cost of R5-R10: heavy unroll + 128-VGPR cap).
// Wave owns 4 q-subtiles x 256-key quarter; kh-partial LDS tree; ones-row
// denominator in V col 8.
// ---------------------------------------------------------------------------
__global__ __launch_bounds__(512, 4)
void qattn_kernel(const float* __restrict__ x, const float* __restrict__ phi,
                  float* __restrict__ aout)
{
    __shared__ __align__(16) _Float16 Klds[NS][8];      // 16 KB, scaled by SQRT_ALPHA
    __shared__ __align__(16) _Float16 Vt[9][1036];      // 18.2 KB: rows0-7 raw k, row8 ones
    __shared__ __align__(16) float4 scratch[2][2][4][64]; // 16 KB partial tree

    const int t    = threadIdx.x;
    const int blk  = blockIdx.x;
    const int qt   = blk & 7;          // 128-query tile
    const int bh   = blk >> 3;
    const int b    = bh >> 4;
    const int h    = bh & 15;
    const int lane = t & 63;
    const int w    = t >> 6;           // 0..7
    const int qg   = w & 1;            // q-subtile group: qsubs qg*4..qg*4+3
    const int kh   = w >> 1;           // key quarter: [kh*256, kh*256+256)

    const float ph0 = phi[0], ph1 = phi[1], ph2 = phi[2], ph3 = phi[3];
    const float ph4 = phi[4], ph5 = phi[5], ph6 = phi[6], ph7 = phi[7];

    // ---- stage K (scaled) and V^T (raw + ones row): two rows per thread ----
    {
        const float* xb = x + ((size_t)b * NS) * NE + h * ND;
        const int k0 = t, k1 = t + 512;
        float4 xa0 = *(const float4*)(xb + (size_t)k0 * NE);
        float4 xc0 = *(const float4*)(xb + (size_t)k0 * NE + 4);
        float4 xa1 = *(const float4*)(xb + (size_t)k1 * NE);
        float4 xc1 = *(const float4*)(xb + (size_t)k1 * NE + 4);
#pragma unroll
        for (int half = 0; half < 2; ++half) {
            const int k = half ? k1 : k0;
            const float4 xa = half ? xa1 : xa0;
            const float4 xc = half ? xc1 : xc0;
            float g0 = __cosf(xa.x + ph0), g1 = __cosf(xa.y + ph1);
            float g2 = __cosf(xa.z + ph2), g3 = __cosf(xa.w + ph3);
            float g4 = __cosf(xc.x + ph4), g5 = __cosf(xc.y + ph5);
            float g6 = __cosf(xc.z + ph6), g7 = __cosf(xc.w + ph7);
            float s7 = g7, s6 = s7 * g6, s5 = s6 * g5, s4 = s5 * g4, s3 = s4 * g3, s2 = s3 * g2;
            float v0 = s2 * g1;                         // wire 0 expectation
            float v1 = g0 * g1, v2 = v1 * g2, v3 = v2 * g3;
            float v4 = v3 * g4, v5 = v4 * g5, v6 = v5 * g6, v7 = v6 * g7;
            half8v row;
            row[0] = (_Float16)(SQRT_ALPHA * v0); row[1] = (_Float16)(SQRT_ALPHA * v1);
            row[2] = (_Float16)(SQRT_ALPHA * v2); row[3] = (_Float16)(SQRT_ALPHA * v3);
            row[4] = (_Float16)(SQRT_ALPHA * v4); row[5] = (_Float16)(SQRT_ALPHA * v5);
            row[6] = (_Float16)(SQRT_ALPHA * v6); row[7] = (_Float16)(SQRT_ALPHA * v7);
            *(half8v*)&Klds[k][0] = row;
            Vt[0][k] = (_Float16)v0; Vt[1][k] = (_Float16)v1;
            Vt[2][k] = (_Float16)v2; Vt[3][k] = (_Float16)v3;
            Vt[4][k] = (_Float16)v4; Vt[5][k] = (_Float16)v5;
            Vt[6][k] = (_Float16)v6; Vt[7][k] = (_Float16)v7;
            Vt[8][k] = (_Float16)1.0f;
        }
    }
    __syncthreads();

    const int e = lane & 15;
    const int g = lane >> 4;
    const half4v zero4 = (half4v)(_Float16)0.0f;

    // Q fragments: B[kd][q], kd=4G+j (G=lane>>4); lanes>=32 (kd 8..15) zero;
    // high half (kd 16..31) zero -> kills kf junk in those slots too.
    half4v qf0 = zero4, qf1 = zero4, qf2 = zero4, qf3 = zero4;
    if (lane < 32) {
        const int qbase = qt * 128 + qg * 64 + e;
        qf0 = *(const half4v*)&Klds[qbase][g * 4];
        qf1 = *(const half4v*)&Klds[qbase + 16][g * 4];
        qf2 = *(const half4v*)&Klds[qbase + 32][g * 4];
        qf3 = *(const half4v*)&Klds[qbase + 48][g * 4];
    }
    const half8v qf80 = cat8(qf0, zero4);
    const half8v qf81 = cat8(qf1, zero4);
    const half8v qf82 = cat8(qf2, zero4);
    const half8v qf83 = cat8(qf3, zero4);

    const _Float16* kp = &Klds[kh * 256 + e][(g & 1) * 4]; // A: K[koff+tile*16+(l&15)][..]
    const int ecl = (e > 8) ? 8 : e;                       // clamp: cols 9..15 unread
    const _Float16* vp = &Vt[ecl][kh * 256 + g * 4];       // B_V: V[key][e]

    float4v acc0 = (float4v)0.0f;
    float4v acc1 = (float4v)0.0f;
    float4v acc2 = (float4v)0.0f;
    float4v acc3 = (float4v)0.0f;
    const float4v zero = (float4v)0.0f;

    // 8 pairs x 32 keys. Rolled loop (unroll 1) to stay under the VGPR cap.
#pragma unroll 1
    for (int p = 0; p < 8; ++p) {
        const _Float16* kpp = kp + p * 256;   // pair = 2 tiles x 16 rows x 8 halves
        const _Float16* vpp = vp + p * 32;

        half4v kf0 = *(const half4v*)(kpp);
        half4v kf1 = *(const half4v*)(kpp + 128);
        half4v vf0 = *(const half4v*)(vpp);
        half4v vf1 = *(const half4v*)(vpp + 16);
        half8v kf80 = cat8(kf0, zero4);
        half8v kf81 = cat8(kf1, zero4);
        half8v vf8  = cat8(vf0, vf1);

        __builtin_amdgcn_s_setprio(1);
        // tile 2p scores
        float4v s00 = MFMA32(kf80, qf80, zero);
        float4v s01 = MFMA32(kf80, qf81, zero);
        float4v s02 = MFMA32(kf80, qf82, zero);
        float4v s03 = MFMA32(kf80, qf83, zero);
        float p000 = EXP2F(s00[0]), p001 = EXP2F(s00[1]), p002 = EXP2F(s00[2]), p003 = EXP2F(s00[3]);
        float p010 = EXP2F(s01[0]), p011 = EXP2F(s01[1]), p012 = EXP2F(s01[2]), p013 = EXP2F(s01[3]);
        float p020 = EXP2F(s02[0]), p021 = EXP2F(s02[1]), p022 = EXP2F(s02[2]), p023 = EXP2F(s02[3]);
        float p030 = EXP2F(s03[0]), p031 = EXP2F(s03[1]), p032 = EXP2F(s03[2]), p033 = EXP2F(s03[3]);
        half4v paA0 = cat4(__builtin_bit_cast(half2v, __builtin_amdgcn_cvt_pkrtz(p000, p001)),
                           __builtin_bit_cast(half2v, __builtin_amdgcn_cvt_pkrtz(p002, p003)));
        half4v paA1 = cat4(__builtin_bit_cast(half2v, __builtin_amdgcn_cvt_pkrtz(p010, p011)),
                           __builtin_bit_cast(half2v, __builtin_amdgcn_cvt_pkrtz(p012, p013)));
        half4v paA2 = cat4(__builtin_bit_cast(half2v, __builtin_amdgcn_cvt_pkrtz(p020, p021)),
                           __builtin_bit_cast(half2v, __builtin_amdgcn_cvt_pkrtz(p022, p023)));
        half4v paA3 = cat4(__builtin_bit_cast(half2v, __builtin_amdgcn_cvt_pkrtz(p030, p031)),
                           __builtin_bit_cast(half2v, __builtin_amdgcn_cvt_pkrtz(p032, p033)));
        // tile 2p+1 scores
        float4v s10 = MFMA32(kf81, qf80, zero);
        float4v s11 = MFMA32(kf81, qf81, zero);
        float4v s12 = MFMA32(kf81, qf82, zero);
        float4v s13 = MFMA32(kf81, qf83, zero);
        float p100 = EXP2F(s10[0]), p101 = EXP2F(s10[1]), p102 = EXP2F(s10[2]), p103 = EXP2F(s10[3]);
        float p110 = EXP2F(s11[0]), p111 = EXP2F(s11[1]), p112 = EXP2F(s11[2]), p113 = EXP2F(s11[3]);
        float p120 = EXP2F(s12[0]), p121 = EXP2F(s12[1]), p122 = EXP2F(s12[2]), p123 = EXP2F(s12[3]);
        float p130 = EXP2F(s13[0]), p131 = EXP2F(s13[1]), p132 = EXP2F(s13[2]), p133 = EXP2F(s13[3]);
        half4v paB0 = cat4(__builtin_bit_cast(half2v, __builtin_amdgcn_cvt_pkrtz(p100, p101)),
                           __builtin_bit_cast(half2v, __builtin_amdgcn_cvt_pkrtz(p102, p103)));
        half4v paB1 = cat4(__builtin_bit_cast(half2v, __builtin_amdgcn_cvt_pkrtz(p110, p111)),
                           __builtin_bit_cast(half2v, __builtin_amdgcn_cvt_pkrtz(p112, p113)));
        half4v paB2 = cat4(__builtin_bit_cast(half2v, __builtin_amdgcn_cvt_pkrtz(p120, p121)),
                           __builtin_bit_cast(half2v, __builtin_amdgcn_cvt_pkrtz(p122, p123)));
        half4v paB3 = cat4(__builtin_bit_cast(half2v, __builtin_amdgcn_cvt_pkrtz(p130, p131)),
                           __builtin_bit_cast(half2v, __builtin_amdgcn_cvt_pkrtz(p132, p133)));

        // PV: one x32 per subtile covers both tiles (32 keys)
        acc0 = MFMA32(cat8(paA0, paB0), vf8, acc0);
        acc1 = MFMA32(cat8(paA1, paB1), vf8, acc1);
        acc2 = MFMA32(cat8(paA2, paB2), vf8, acc2);
        acc3 = MFMA32(cat8(paA3, paB3), vf8, acc3);
        __builtin_amdgcn_s_setprio(0);
    }

    // ---- kh-partial tree (unnormalized sums incl. denom col), 2 barriers ----
    if (kh >= 2) {
        scratch[kh - 2][qg][0][lane] = make_float4(acc0[0], acc0[1], acc0[2], acc0[3]);
        scratch[kh - 2][qg][1][lane] = make_float4(acc1[0], acc1[1], acc1[2], acc1[3]);
        scratch[kh - 2][qg][2][lane] = make_float4(acc2[0], acc2[1], acc2[2], acc2[3]);
        scratch[kh - 2][qg][3][lane] = make_float4(acc3[0], acc3[1], acc3[2], acc3[3]);
    }
    __syncthreads();
    if (kh < 2) {
        float4 c0 = scratch[kh][qg][0][lane];
        float4 c1 = scratch[kh][qg][1][lane];
        float4 c2 = scratch[kh][qg][2][lane];
        float4 c3 = scratch[kh][qg][3][lane];
        acc0[0] += c0.x; acc0[1] += c0.y; acc0[2] += c0.z; acc0[3] += c0.w;
        acc1[0] += c1.x; acc1[1] += c1.y; acc1[2] += c1.z; acc1[3] += c1.w;
        acc2[0] += c2.x; acc2[1] += c2.y; acc2[2] += c2.z; acc2[3] += c2.w;
        acc3[0] += c3.x; acc3[1] += c3.y; acc3[2] += c3.z; acc3[3] += c3.w;
    }
    if (kh == 1) {   // rewrite region [1] (only this wave read it)
        scratch[1][qg][0][lane] = make_float4(acc0[0], acc0[1], acc0[2], acc0[3]);
        scratch[1][qg][1][lane] = make_float4(acc1[0], acc1[1], acc1[2], acc1[3]);
        scratch[1][qg][2][lane] = make_float4(acc2[0], acc2[1], acc2[2], acc2[3]);
        scratch[1][qg][3][lane] = make_float4(acc3[0], acc3[1], acc3[2], acc3[3]);
    }
    __syncthreads();
    if (kh == 0) {
        float4 c0 = scratch[1][qg][0][lane];
        float4 c1 = scratch[1][qg][1][lane];
        float4 c2 = scratch[1][qg][2][lane];
        float4 c3 = scratch[1][qg][3][lane];
        acc0[0] += c0.x; acc0[1] += c0.y; acc0[2] += c0.z; acc0[3] += c0.w;
        acc1[0] += c1.x; acc1[1] += c1.y; acc1[2] += c1.z; acc1[3] += c1.w;
        acc2[0] += c2.x; acc2[1] += c2.y; acc2[2] += c2.z; acc2[3] += c2.w;
        acc3[0] += c3.x; acc3[1] += c3.y; acc3[2] += c3.z; acc3[3] += c3.w;

        const int src = (lane & 48) | 8;
        const size_t rb = (size_t)(b * NS + qt * 128 + qg * 64 + g * 4);
        float* opb = aout + rb * NE + h * ND + e;
#pragma unroll
        for (int qs = 0; qs < 4; ++qs) {
            float4v a = (qs == 0) ? acc0 : (qs == 1) ? acc1 : (qs == 2) ? acc2 : acc3;
            float d0 = __shfl(a[0], src, 64);
            float d1 = __shfl(a[1], src, 64);
            float d2 = __shfl(a[2], src, 64);
            float d3 = __shfl(a[3], src, 64);
            if (e < 8) {
                float* op = opb + (size_t)(qs * 16) * NE;
                op[0 * NE] = a[0] / d0;
                op[1 * NE] = a[1] / d1;
                op[2 * NE] = a[2] / d2;
                op[3 * NE] = a[3] / d3;
            }
        }
    }
}

// ---------------------------------------------------------------------------
// out = A @ W^T + b via f16 MFMA (R10, verified: -3.2us vs f32-FMA version).
// Block = 256 thr = 4 waves; 16 rows x 128 cols; wave wv owns n-quarter.
// ---------------------------------------------------------------------------
__global__ __launch_bounds__(256)
void proj_kernel(const float* __restrict__ A, const float* __restrict__ W,
                 const float* __restrict__ bias, float* __restrict__ out)
{
    __shared__ __align__(16) _Float16 Wh[NE][140];   // 35 KB: Wh[n][k]
    __shared__ __align__(16) _Float16 As[16][140];   // 4.4 KB: As[m][k]

    const int t  = threadIdx.x;
    const int r0 = blockIdx.x * 16;

    for (int i = t; i < 16 * 32; i += 256) {
        int m = i >> 5, k4 = (i & 31) * 4;
        float4 a4 = *(const float4*)&A[(size_t)(r0 + m) * NE + k4];
        half2v h01 = __builtin_bit_cast(half2v, __builtin_amdgcn_cvt_pkrtz(a4.x, a4.y));
        half2v h23 = __builtin_bit_cast(half2v, __builtin_amdgcn_cvt_pkrtz(a4.z, a4.w));
        *(half4v*)&As[m][k4] = __builtin_shufflevector(h01, h23, 0, 1, 2, 3);
    }
    for (int i = t; i < NE * 32; i += 256) {
        int n = i >> 5, k4 = (i & 31) * 4;
        float4 w4 = *(const float4*)&W[(size_t)n * NE + k4];
        half2v h01 = __builtin_bit_cast(half2v, __builtin_amdgcn_cvt_pkrtz(w4.x, w4.y));
        half2v h23 = __builtin_bit_cast(half2v, __builtin_amdgcn_cvt_pkrtz(w4.z, w4.w));
        *(half4v*)&Wh[n][k4] = __builtin_shufflevector(h01, h23, 0, 1, 2, 3);
    }
    __syncthreads();

    const int lane = t & 63;
    const int wv   = t >> 6;        // n-quarter
    const int e    = lane & 15;
    const int g    = lane >> 4;

    float4v acc0 = (float4v)0.0f;
    float4v acc1 = (float4v)0.0f;

#pragma unroll
    for (int c = 0; c < 8; ++c) {
        half4v af  = *(const half4v*)&As[e][c * 16 + g * 4];
        half4v bf0 = *(const half4v*)&Wh[wv * 32 + e][c * 16 + g * 4];
        half4v bf1 = *(const half4v*)&Wh[wv * 32 + 16 + e][c * 16 + g * 4];
        acc0 = __builtin_amdgcn_mfma_f32_16x16x16f16(af, bf0, acc0, 0, 0, 0);
        acc1 = __builtin_amdgcn_mfma_f32_16x16x16f16(af, bf1, acc1, 0, 0, 0);
    }

    const float bv0 = bias[wv * 32 + e];
    const float bv1 = bias[wv * 32 + 16 + e];
    float* ob = out + (size_t)(r0 + g * 4) * NE + wv * 32 + e;
#pragma unroll
    for (int r = 0; r < 4; ++r) {
        ob[(size_t)r * NE]      = acc0[r] + bv0;
        ob[(size_t)r * NE + 16] = acc1[r] + bv1;
    }
}

extern "C" void kernel_launch(void* const* d_in, const int* in_sizes, int n_in,
                              void* d_out, int out_size, void* d_ws, size_t ws_size,
                              hipStream_t stream)
{
    (void)in_sizes; (void)n_in; (void)out_size; (void)d_ws; (void)ws_size;
    const float* x   = (const float*)d_in[0];
    const float* phi = (const float*)d_in[1];
    const float* W   = (const float*)d_in[2];
    const float* b   = (const float*)d_in[3];
    float* out = (float*)d_out;

    qattn_kernel<<<dim3(NB * NH * 8), dim3(512), 0, stream>>>(x, phi, out);
    proj_kernel<<<dim3(NB * NS / 16), dim3(256), 0, stream>>>(out, W, b, out);
}

// Round 12
// 20.882 us; speedup vs baseline: 1.0499x; 1.0499x over previous
//
#include <hip/hip_runtime.h>

#define NB 4
#define NS 1024
#define NE 128
#define NH 16
#define ND 8

typedef __attribute__((ext_vector_type(4))) _Float16 half4v;
typedef __attribute__((ext_vector_type(8))) _Float16 half8v;
typedef __attribute__((ext_vector_type(2))) _Float16 half2v;
typedef __attribute__((ext_vector_type(4))) float float4v;

#if __has_builtin(__builtin_amdgcn_exp2f)
#define EXP2F(x) __builtin_amdgcn_exp2f(x)
#else
#define EXP2F(x) __expf(0.69314718055994531f * (x))
#endif

// sqrt(log2(e)/sqrt(8)): both QK^T operands carry this -> MFMA out feeds 2^x directly
#define SQRT_ALPHA 0.71423656f

#define MFMA16(A, B, C) __builtin_amdgcn_mfma_f32_16x16x16f16((A), (B), (C), 0, 0, 0)
#define MFMA32(A, B, C) __builtin_amdgcn_mfma_f32_16x16x32_f16((A), (B), (C), 0, 0, 0)

static __device__ __forceinline__ half8v cat8(half4v lo, half4v hi) {
    return __builtin_shufflevector(lo, hi, 0, 1, 2, 3, 4, 5, 6, 7);
}
static __device__ __forceinline__ half4v cat4(half2v lo, half2v hi) {
    return __builtin_shufflevector(lo, hi, 0, 1, 2, 3);
}

// ---------------------------------------------------------------------------
// Fused quantum-layer + self-attention. R12: TRUE 8 waves/SIMD.
// R8's (1024,8) attempt had ~100 live regs under a 64-VGPR cap -> hot-loop
// spills; every clean round ran only 4 waves/SIMD (4096 waves total) with
// phase-locked 400-600cy MFMA->exp->PV chains = stall-bound (~27% issue eff).
// Now: 16 waves/block = qg(0..3: 32 queries) x kh(0..3: 256 keys); per-wave
// body holds ~54 live VGPRs (2 qf, 4 s, 2 acc, kf/vf) -> fits cap, no spill;
// 512 blocks x 16 waves = 8192 waves = 8/SIMD.
// Klds stride-12 halves: kf-read banks (6e)%32 all-distinct (was 4-way).
// QK on x16 mfma; PV on x32 (pair trick, validated R10/R11). Ones-row in V
// col 8 = softmax denominator. kh-partials via 2-barrier LDS tree.
// ---------------------------------------------------------------------------
__global__ __launch_bounds__(1024, 8)
void qattn_kernel(const float* __restrict__ x, const float* __restrict__ phi,
                  float* __restrict__ aout)
{
    __shared__ __align__(16) _Float16 KA[NS * 12];      // 24 KB, stride 12, scaled
    __shared__ __align__(16) _Float16 Vt[9][1036];      // 18.2 KB: rows0-7 raw, row8 ones
    __shared__ __align__(16) float4 scratch[2][4][2][64]; // 16 KB partial tree

    const int t    = threadIdx.x;
    const int blk  = blockIdx.x;
    const int qt   = blk & 7;          // 128-query tile
    const int bh   = blk >> 3;
    const int b    = bh >> 4;
    const int h    = bh & 15;
    const int lane = t & 63;
    const int w    = t >> 6;           // 0..15
    const int qg   = w & 3;            // 32-query group (2 subtiles)
    const int kh   = w >> 2;           // key quarter [kh*256, +256)

    // ---- stage K (scaled, stride 12) and V^T (raw + ones row): 1 row/thread ----
    {
        const int k = t;
        const float* xr = x + ((size_t)(b * NS + k)) * NE + h * ND;
        float4 xa = *(const float4*)xr;
        float4 xc = *(const float4*)(xr + 4);
        float g0 = __cosf(xa.x + phi[0]), g1 = __cosf(xa.y + phi[1]);
        float g2 = __cosf(xa.z + phi[2]), g3 = __cosf(xa.w + phi[3]);
        float g4 = __cosf(xc.x + phi[4]), g5 = __cosf(xc.y + phi[5]);
        float g6 = __cosf(xc.z + phi[6]), g7 = __cosf(xc.w + phi[7]);
        float s7 = g7, s6 = s7 * g6, s5 = s6 * g5, s4 = s5 * g4, s3 = s4 * g3, s2 = s3 * g2;
        float v0 = s2 * g1;                         // wire 0 expectation
        float v1 = g0 * g1, v2 = v1 * g2, v3 = v2 * g3;
        float v4 = v3 * g4, v5 = v4 * g5, v6 = v5 * g6, v7 = v6 * g7;
        half4v rlo, rhi;
        rlo[0] = (_Float16)(SQRT_ALPHA * v0); rlo[1] = (_Float16)(SQRT_ALPHA * v1);
        rlo[2] = (_Float16)(SQRT_ALPHA * v2); rlo[3] = (_Float16)(SQRT_ALPHA * v3);
        rhi[0] = (_Float16)(SQRT_ALPHA * v4); rhi[1] = (_Float16)(SQRT_ALPHA * v5);
        rhi[2] = (_Float16)(SQRT_ALPHA * v6); rhi[3] = (_Float16)(SQRT_ALPHA * v7);
        *(half4v*)&KA[k * 12]     = rlo;
        *(half4v*)&KA[k * 12 + 4] = rhi;
        Vt[0][k] = (_Float16)v0; Vt[1][k] = (_Float16)v1;
        Vt[2][k] = (_Float16)v2; Vt[3][k] = (_Float16)v3;
        Vt[4][k] = (_Float16)v4; Vt[5][k] = (_Float16)v5;
        Vt[6][k] = (_Float16)v6; Vt[7][k] = (_Float16)v7;
        Vt[8][k] = (_Float16)1.0f;
    }
    __syncthreads();

    const int e = lane & 15;
    const int g = lane >> 4;

    // Q fragments (B operand of S^T = K.Q^T): lanes>=32 (kd 8..15) zero.
    half4v qf0 = (half4v)(_Float16)0.0f;
    half4v qf1 = (half4v)(_Float16)0.0f;
    if (lane < 32) {
        const int qrow = qt * 128 + qg * 32 + e;
        qf0 = *(const half4v*)&KA[qrow * 12 + g * 4];
        qf1 = *(const half4v*)&KA[(qrow + 16) * 12 + g * 4];
    }

    const _Float16* kp = &KA[(kh * 256 + e) * 12 + (g & 1) * 4]; // K[key][..]
    const int ecl = (e > 8) ? 8 : e;                             // cols 9..15 unread
    const _Float16* vp = &Vt[ecl][kh * 256 + g * 4];             // V[key][e]

    float4v acc0 = (float4v)0.0f;
    float4v acc1 = (float4v)0.0f;
    const float4v zero = (float4v)0.0f;

    // 8 pairs x 32 keys; one kf/vf read feeds 2 q-subtiles; rolled (VGPR cap).
#pragma unroll 1
    for (int p = 0; p < 8; ++p) {
        const _Float16* kpp = kp + p * 384;   // 32 rows * 12 halves
        const _Float16* vpp = vp + p * 32;

        half4v kf0 = *(const half4v*)(kpp);
        half4v kf1 = *(const half4v*)(kpp + 192);
        half4v vf0 = *(const half4v*)(vpp);
        half4v vf1 = *(const half4v*)(vpp + 16);

        float4v s00 = MFMA16(kf0, qf0, zero);   // tile 2p,   subtile 0
        float4v s01 = MFMA16(kf0, qf1, zero);   // tile 2p,   subtile 1
        float4v s10 = MFMA16(kf1, qf0, zero);   // tile 2p+1, subtile 0
        float4v s11 = MFMA16(kf1, qf1, zero);   // tile 2p+1, subtile 1

        float p000 = EXP2F(s00[0]), p001 = EXP2F(s00[1]), p002 = EXP2F(s00[2]), p003 = EXP2F(s00[3]);
        float p010 = EXP2F(s01[0]), p011 = EXP2F(s01[1]), p012 = EXP2F(s01[2]), p013 = EXP2F(s01[3]);
        float p100 = EXP2F(s10[0]), p101 = EXP2F(s10[1]), p102 = EXP2F(s10[2]), p103 = EXP2F(s10[3]);
        float p110 = EXP2F(s11[0]), p111 = EXP2F(s11[1]), p112 = EXP2F(s11[2]), p113 = EXP2F(s11[3]);

        half4v paA0 = cat4(__builtin_bit_cast(half2v, __builtin_amdgcn_cvt_pkrtz(p000, p001)),
                           __builtin_bit_cast(half2v, __builtin_amdgcn_cvt_pkrtz(p002, p003)));
        half4v paA1 = cat4(__builtin_bit_cast(half2v, __builtin_amdgcn_cvt_pkrtz(p010, p011)),
                           __builtin_bit_cast(half2v, __builtin_amdgcn_cvt_pkrtz(p012, p013)));
        half4v paB0 = cat4(__builtin_bit_cast(half2v, __builtin_amdgcn_cvt_pkrtz(p100, p101)),
                           __builtin_bit_cast(half2v, __builtin_amdgcn_cvt_pkrtz(p102, p103)));
        half4v paB1 = cat4(__builtin_bit_cast(half2v, __builtin_amdgcn_cvt_pkrtz(p110, p111)),
                           __builtin_bit_cast(half2v, __builtin_amdgcn_cvt_pkrtz(p112, p113)));

        half8v vf8 = cat8(vf0, vf1);
        acc0 = MFMA32(cat8(paA0, paB0), vf8, acc0);   // 32 keys in one PV
        acc1 = MFMA32(cat8(paA1, paB1), vf8, acc1);
    }

    // ---- kh-partial tree (unnormalized sums incl. denom col), 2 barriers ----
    if (kh >= 2) {
        scratch[kh - 2][qg][0][lane] = make_float4(acc0[0], acc0[1], acc0[2], acc0[3]);
        scratch[kh - 2][qg][1][lane] = make_float4(acc1[0], acc1[1], acc1[2], acc1[3]);
    }
    __syncthreads();
    if (kh < 2) {
        float4 c0 = scratch[kh][qg][0][lane];
        float4 c1 = scratch[kh][qg][1][lane];
        acc0[0] += c0.x; acc0[1] += c0.y; acc0[2] += c0.z; acc0[3] += c0.w;
        acc1[0] += c1.x; acc1[1] += c1.y; acc1[2] += c1.z; acc1[3] += c1.w;
    }
    if (kh == 1) {   // rewrite region [1] (only this wave read it)
        scratch[1][qg][0][lane] = make_float4(acc0[0], acc0[1], acc0[2], acc0[3]);
        scratch[1][qg][1][lane] = make_float4(acc1[0], acc1[1], acc1[2], acc1[3]);
    }
    __syncthreads();
    if (kh == 0) {
        float4 c0 = scratch[1][qg][0][lane];
        float4 c1 = scratch[1][qg][1][lane];
        acc0[0] += c0.x; acc0[1] += c0.y; acc0[2] += c0.z; acc0[3] += c0.w;
        acc1[0] += c1.x; acc1[1] += c1.y; acc1[2] += c1.z; acc1[3] += c1.w;

        const int src = (lane & 48) | 8;
        const size_t rb = (size_t)(b * NS + qt * 128 + qg * 32 + g * 4);
        float* opb = aout + rb * NE + h * ND + e;
#pragma unroll
        for (int qs = 0; qs < 2; ++qs) {
            float4v a = qs ? acc1 : acc0;
            float d0 = __shfl(a[0], src, 64);
            float d1 = __shfl(a[1], src, 64);
            float d2 = __shfl(a[2], src, 64);
            float d3 = __shfl(a[3], src, 64);
            if (e < 8) {
                float* op = opb + (size_t)(qs * 16) * NE;
                op[0 * NE] = a[0] / d0;
                op[1 * NE] = a[1] / d1;
                op[2 * NE] = a[2] / d2;
                op[3 * NE] = a[3] / d3;
            }
        }
    }
}

// ---------------------------------------------------------------------------
// out = A @ W^T + b via f16 MFMA (R10, verified: -3.2us vs f32-FMA version).
// Block = 256 thr = 4 waves; 16 rows x 128 cols; wave wv owns n-quarter.
// ---------------------------------------------------------------------------
__global__ __launch_bounds__(256)
void proj_kernel(const float* __restrict__ A, const float* __restrict__ W,
                 const float* __restrict__ bias, float* __restrict__ out)
{
    __shared__ __align__(16) _Float16 Wh[NE][140];   // 35 KB: Wh[n][k]
    __shared__ __align__(16) _Float16 As[16][140];   // 4.4 KB: As[m][k]

    const int t  = threadIdx.x;
    const int r0 = blockIdx.x * 16;

    for (int i = t; i < 16 * 32; i += 256) {
        int m = i >> 5, k4 = (i & 31) * 4;
        float4 a4 = *(const float4*)&A[(size_t)(r0 + m) * NE + k4];
        half2v h01 = __builtin_bit_cast(half2v, __builtin_amdgcn_cvt_pkrtz(a4.x, a4.y));
        half2v h23 = __builtin_bit_cast(half2v, __builtin_amdgcn_cvt_pkrtz(a4.z, a4.w));
        *(half4v*)&As[m][k4] = __builtin_shufflevector(h01, h23, 0, 1, 2, 3);
    }
    for (int i = t; i < NE * 32; i += 256) {
        int n = i >> 5, k4 = (i & 31) * 4;
        float4 w4 = *(const float4*)&W[(size_t)n * NE + k4];
        half2v h01 = __builtin_bit_cast(half2v, __builtin_amdgcn_cvt_pkrtz(w4.x, w4.y));
        half2v h23 = __builtin_bit_cast(half2v, __builtin_amdgcn_cvt_pkrtz(w4.z, w4.w));
        *(half4v*)&Wh[n][k4] = __builtin_shufflevector(h01, h23, 0, 1, 2, 3);
    }
    __syncthreads();

    const int lane = t & 63;
    const int wv   = t >> 6;        // n-quarter
    const int e    = lane & 15;
    const int g    = lane >> 4;

    float4v acc0 = (float4v)0.0f;
    float4v acc1 = (float4v)0.0f;

#pragma unroll
    for (int c = 0; c < 8; ++c) {
        half4v af  = *(const half4v*)&As[e][c * 16 + g * 4];
        half4v bf0 = *(const half4v*)&Wh[wv * 32 + e][c * 16 + g * 4];
        half4v bf1 = *(const half4v*)&Wh[wv * 32 + 16 + e][c * 16 + g * 4];
        acc0 = __builtin_amdgcn_mfma_f32_16x16x16f16(af, bf0, acc0, 0, 0, 0);
        acc1 = __builtin_amdgcn_mfma_f32_16x16x16f16(af, bf1, acc1, 0, 0, 0);
    }

    const float bv0 = bias[wv * 32 + e];
    const float bv1 = bias[wv * 32 + 16 + e];
    float* ob = out + (size_t)(r0 + g * 4) * NE + wv * 32 + e;
#pragma unroll
    for (int r = 0; r < 4; ++r) {
        ob[(size_t)r * NE]      = acc0[r] + bv0;
        ob[(size_t)r * NE + 16] = acc1[r] + bv1;
    }
}

extern "C" void kernel_launch(void* const* d_in, const int* in_sizes, int n_in,
                              void* d_out, int out_size, void* d_ws, size_t ws_size,
                              hipStream_t stream)
{
    (void)in_sizes; (void)n_in; (void)out_size; (void)d_ws; (void)ws_size;
    const float* x   = (const float*)d_in[0];
    const float* phi = (const float*)d_in[1];
    const float* W   = (const float*)d_in[2];
    const float* b   = (const float*)d_in[3];
    float* out = (float*)d_out;

    qattn_kernel<<<dim3(NB * NH * 8), dim3(1024), 0, stream>>>(x, phi, out);
    proj_kernel<<<dim3(NB * NS / 16), dim3(256), 0, stream>>>(out, W, b, out);
}